// Round 8
// baseline (355.795 us; speedup 1.0000x reference)
//
#include <hip/hip_runtime.h>
#include <hip/hip_bf16.h>

#define BATCH 4
#define S_LEN 2048
#define D_DIM 1024
#define NHEAD 16
#define HDIM 64

// Q pre-scale: 1/sqrt(HDIM) * log2(e), so softmax works in exp2 domain.
#define QSCALE 0.18033688011112042f

typedef __attribute__((ext_vector_type(8))) __bf16 bf16x8;
typedef __attribute__((ext_vector_type(4))) __bf16 bf16x4;
typedef __attribute__((ext_vector_type(4))) float f32x4;

static __device__ inline unsigned int bf16_bits(float f) {
    __bf16 h = (__bf16)f;
    return (unsigned int)__builtin_bit_cast(unsigned short, h);
}

// ---------------------------------------------------------------------------
// fp32 -> bf16 bulk convert, 8 elems/thread, 16B stores.
// ---------------------------------------------------------------------------
__global__ __launch_bounds__(256) void cvt_kernel(
    const float* __restrict__ src, __bf16* __restrict__ dst, int n8)
{
    int i = blockIdx.x * 256 + threadIdx.x;
    if (i >= n8) return;
    const f32x4* p = reinterpret_cast<const f32x4*>(src + (size_t)i * 8);
    f32x4 a = p[0], b = p[1];
    bf16x8 r;
    r[0] = (__bf16)a[0]; r[1] = (__bf16)a[1]; r[2] = (__bf16)a[2]; r[3] = (__bf16)a[3];
    r[4] = (__bf16)b[0]; r[5] = (__bf16)b[1]; r[6] = (__bf16)b[2]; r[7] = (__bf16)b[3];
    *reinterpret_cast<bf16x8*>(dst + (size_t)i * 8) = r;
}

// ---------------------------------------------------------------------------
// Projection GEMM (m97-style): C[m][n] = sum_d xb[m][d] * wb[n][d]
// q output is pre-scaled by QSCALE. q,k -> [bh][s][e]; v -> [bh][e][s].
// ---------------------------------------------------------------------------
__global__ __launch_bounds__(256) void proj_gemm_kernel(
    const __bf16* __restrict__ xb, const __bf16* __restrict__ wb,
    __bf16* __restrict__ qo, __bf16* __restrict__ ko, __bf16* __restrict__ vto)
{
    __shared__ __bf16 As[128][32];
    __shared__ __bf16 Bs[128][32];

    const int tid = threadIdx.x;
    const int l  = tid & 63;
    const int w  = tid >> 6;
    const int wm = w >> 1, wn = w & 1;
    const int lr = l & 15, lg = l >> 4, lk = lg * 8;
    const int m0 = blockIdx.y * 128;
    const int n0 = blockIdx.x * 128;
    const int mat = n0 >> 10;           // 0=q,1=k,2=v
    const int nb  = n0 & 1023;

    const int sr = l >> 2;
    const int sc = (l & 3) * 8;
    const int g0 = w * 2;

    f32x4 acc[4][4] = {};

    for (int d = 0; d < D_DIM; d += 32) {
        __builtin_amdgcn_global_load_lds(
            (const __attribute__((address_space(1))) void*)(xb + (size_t)(m0 + g0 * 16 + sr) * D_DIM + d + sc),
            (__attribute__((address_space(3))) void*)(&As[g0 * 16][0]), 16, 0, 0);
        __builtin_amdgcn_global_load_lds(
            (const __attribute__((address_space(1))) void*)(xb + (size_t)(m0 + (g0 + 1) * 16 + sr) * D_DIM + d + sc),
            (__attribute__((address_space(3))) void*)(&As[(g0 + 1) * 16][0]), 16, 0, 0);
        __builtin_amdgcn_global_load_lds(
            (const __attribute__((address_space(1))) void*)(wb + (size_t)(n0 + g0 * 16 + sr) * D_DIM + d + sc),
            (__attribute__((address_space(3))) void*)(&Bs[g0 * 16][0]), 16, 0, 0);
        __builtin_amdgcn_global_load_lds(
            (const __attribute__((address_space(1))) void*)(wb + (size_t)(n0 + (g0 + 1) * 16 + sr) * D_DIM + d + sc),
            (__attribute__((address_space(3))) void*)(&Bs[(g0 + 1) * 16][0]), 16, 0, 0);
        __syncthreads();

        bf16x8 af[4], bfr[4];
        #pragma unroll
        for (int mi = 0; mi < 4; ++mi)
            af[mi] = *reinterpret_cast<const bf16x8*>(&As[wm * 64 + mi * 16 + lr][lk]);
        #pragma unroll
        for (int ni = 0; ni < 4; ++ni)
            bfr[ni] = *reinterpret_cast<const bf16x8*>(&Bs[wn * 64 + ni * 16 + lr][lk]);
        #pragma unroll
        for (int mi = 0; mi < 4; ++mi) {
            #pragma unroll
            for (int ni = 0; ni < 4; ++ni)
                acc[mi][ni] = __builtin_amdgcn_mfma_f32_16x16x32_bf16(
                    af[mi], bfr[ni], acc[mi][ni], 0, 0, 0);
        }
        __syncthreads();
    }

    const float oscale = (mat == 0) ? QSCALE : 1.0f;
    #pragma unroll
    for (int mi = 0; mi < 4; ++mi) {
        const int mrow = m0 + wm * 64 + mi * 16 + lg * 4;
        const int b = mrow >> 11;
        const int s = mrow & (S_LEN - 1);
        #pragma unroll
        for (int ni = 0; ni < 4; ++ni) {
            const int n = nb + wn * 64 + ni * 16 + lr;
            const int h = n >> 6;
            const int e = n & 63;
            if (mat == 2) {
                bf16x4 pk;
                #pragma unroll
                for (int r = 0; r < 4; ++r) pk[r] = (__bf16)acc[mi][ni][r];
                *reinterpret_cast<bf16x4*>(
                    vto + ((size_t)(b * NHEAD + h) * HDIM + e) * S_LEN + s) = pk;
            } else {
                __bf16* __restrict__ dst = (mat == 0) ? qo : ko;
                #pragma unroll
                for (int r = 0; r < 4; ++r)
                    dst[((size_t)(b * NHEAD + h) * S_LEN + (s + r)) * HDIM + e] =
                        (__bf16)(acc[mi][ni][r] * oscale);
            }
        }
    }
}

// ---------------------------------------------------------------------------
// Attention helpers: named register sets for double-buffered K prefetch.
// ---------------------------------------------------------------------------
struct KFrag { bf16x8 a0[4]; bf16x8 a1[4]; };   // 32 VGPR
struct VFrag { bf16x8 v0[4]; bf16x8 v1[4]; };   // 32 VGPR

__device__ __attribute__((always_inline)) inline void load_k(
    KFrag& kf, const __bf16* __restrict__ kp, int kv0, int lr, int lk)
{
    #pragma unroll
    for (int c = 0; c < 4; ++c) {
        const __bf16* krow = kp + (size_t)(kv0 + c * 16 + lr) * HDIM;
        kf.a0[c] = *reinterpret_cast<const bf16x8*>(krow + lk);
        kf.a1[c] = *reinterpret_cast<const bf16x8*>(krow + 32 + lk);
    }
}

// ---------------------------------------------------------------------------
// One KV iteration (64 kv) for a QUAD of 16-row q-tiles, K prefetched.
// V issued at top (covered by softmax); softmax stage-major in tile PAIRS
// (two shfl chains in flight); psum cross-lane reduce deferred past PV.
// ---------------------------------------------------------------------------
template<bool MASK>
__device__ __attribute__((always_inline)) inline void quad_compute(
    int kv0, int qbase, int lr, int lg, int lk, int swz,
    const __bf16* __restrict__ vp, const KFrag& kf,
    const bf16x8 (&bq0)[4], const bf16x8 (&bq1)[4],
    float (&m_acc)[4], float (&l_acc)[4], f32x4 (&acc)[4][4],
    __bf16* pl_base)
{
    // ---- V early issue (consumed only at PV) ----
    VFrag vf;
    #pragma unroll
    for (int ni = 0; ni < 4; ++ni) {
        const __bf16* vrow = vp + (size_t)(ni * 16 + lr) * S_LEN + kv0;
        vf.v0[ni] = *reinterpret_cast<const bf16x8*>(vrow + lk);
        vf.v1[ni] = *reinterpret_cast<const bf16x8*>(vrow + 32 + lk);
    }

    float sc_t[4], psum_t[4];

    #pragma unroll
    for (int pp = 0; pp < 2; ++pp) {
        const int i0 = pp * 2, i1 = pp * 2 + 1;
        f32x4 sA[4], sB[4];

        __builtin_amdgcn_s_setprio(1);
        #pragma unroll
        for (int c = 0; c < 4; ++c) {
            f32x4 t0 = {}, t1 = {};
            t0 = __builtin_amdgcn_mfma_f32_16x16x32_bf16(kf.a0[c], bq0[i0], t0, 0, 0, 0);
            t0 = __builtin_amdgcn_mfma_f32_16x16x32_bf16(kf.a1[c], bq1[i0], t0, 0, 0, 0);
            t1 = __builtin_amdgcn_mfma_f32_16x16x32_bf16(kf.a0[c], bq0[i1], t1, 0, 0, 0);
            t1 = __builtin_amdgcn_mfma_f32_16x16x32_bf16(kf.a1[c], bq1[i1], t1, 0, 0, 0);
            sA[c] = t0; sB[c] = t1;
        }
        __builtin_amdgcn_s_setprio(0);

        if (MASK) {
            const int qrA = qbase + i0 * 16 + lr;
            const int qrB = qbase + i1 * 16 + lr;
            #pragma unroll
            for (int c = 0; c < 4; ++c)
                #pragma unroll
                for (int r = 0; r < 4; ++r) {
                    const int kvp = kv0 + c * 16 + lg * 4 + r;
                    if (kvp > qrA) sA[c][r] = -1e30f;
                    if (kvp > qrB) sB[c][r] = -1e30f;
                }
        }

        // ---- two interleaved max trees + shfl chains ----
        float mxA = fmaxf(
            fmaxf(fmaxf(fmaxf(sA[0][0], sA[0][1]), fmaxf(sA[0][2], sA[0][3])),
                  fmaxf(fmaxf(sA[1][0], sA[1][1]), fmaxf(sA[1][2], sA[1][3]))),
            fmaxf(fmaxf(fmaxf(sA[2][0], sA[2][1]), fmaxf(sA[2][2], sA[2][3])),
                  fmaxf(fmaxf(sA[3][0], sA[3][1]), fmaxf(sA[3][2], sA[3][3]))));
        float mxB = fmaxf(
            fmaxf(fmaxf(fmaxf(sB[0][0], sB[0][1]), fmaxf(sB[0][2], sB[0][3])),
                  fmaxf(fmaxf(sB[1][0], sB[1][1]), fmaxf(sB[1][2], sB[1][3]))),
            fmaxf(fmaxf(fmaxf(sB[2][0], sB[2][1]), fmaxf(sB[2][2], sB[2][3])),
                  fmaxf(fmaxf(sB[3][0], sB[3][1]), fmaxf(sB[3][2], sB[3][3]))));
        float tA = __shfl_xor(mxA, 16);
        float tB = __shfl_xor(mxB, 16);
        mxA = fmaxf(mxA, tA);
        mxB = fmaxf(mxB, tB);
        tA = __shfl_xor(mxA, 32);
        tB = __shfl_xor(mxB, 32);
        mxA = fmaxf(mxA, tA);
        mxB = fmaxf(mxB, tB);

        const float mnA = fmaxf(m_acc[i0], mxA);
        const float mnB = fmaxf(m_acc[i1], mxB);
        sc_t[i0] = exp2f(m_acc[i0] - mnA);
        sc_t[i1] = exp2f(m_acc[i1] - mnB);
        m_acc[i0] = mnA;
        m_acc[i1] = mnB;

        // ---- exp2 + pack + LDS store, both tiles; per-lane psum only ----
        __bf16* plA = pl_base + i0 * (16 * 64);
        __bf16* plB = pl_base + i1 * (16 * 64);
        float psA = 0.0f, psB = 0.0f;
        #pragma unroll
        for (int c = 0; c < 4; ++c) {
            const float a0 = exp2f(sA[c][0] - mnA);
            const float a1 = exp2f(sA[c][1] - mnA);
            const float a2 = exp2f(sA[c][2] - mnA);
            const float a3 = exp2f(sA[c][3] - mnA);
            const float b0 = exp2f(sB[c][0] - mnB);
            const float b1 = exp2f(sB[c][1] - mnB);
            const float b2 = exp2f(sB[c][2] - mnB);
            const float b3 = exp2f(sB[c][3] - mnB);
            psA += (a0 + a1) + (a2 + a3);
            psB += (b0 + b1) + (b2 + b3);
            uint2 pkA, pkB;
            pkA.x = bf16_bits(a0) | (bf16_bits(a1) << 16);
            pkA.y = bf16_bits(a2) | (bf16_bits(a3) << 16);
            pkB.x = bf16_bits(b0) | (bf16_bits(b1) << 16);
            pkB.y = bf16_bits(b2) | (bf16_bits(b3) << 16);
            const int col = (c * 16 + lg * 4) ^ swz;
            *reinterpret_cast<uint2*>(plA + lr * 64 + col) = pkA;
            *reinterpret_cast<uint2*>(plB + lr * 64 + col) = pkB;
        }
        psum_t[i0] = psA;
        psum_t[i1] = psB;

        // ---- rescale acc (per-lane q-row: plain vector mul) ----
        #pragma unroll
        for (int ni = 0; ni < 4; ++ni) {
            acc[i0][ni] *= sc_t[i0];
            acc[i1][ni] *= sc_t[i1];
        }
    }

    // ---- PV (swapped): shared V fragments, acc cols = own q-row ----
    __builtin_amdgcn_s_setprio(1);
    #pragma unroll
    for (int i = 0; i < 4; ++i) {
        __bf16* pl = pl_base + i * (16 * 64);
        const bf16x8 pa0 = *reinterpret_cast<const bf16x8*>(pl + lr * 64 + ((0 + lk) ^ swz));
        const bf16x8 pa1 = *reinterpret_cast<const bf16x8*>(pl + lr * 64 + ((32 + lk) ^ swz));
        #pragma unroll
        for (int ni = 0; ni < 4; ++ni) {
            acc[i][ni] = __builtin_amdgcn_mfma_f32_16x16x32_bf16(vf.v0[ni], pa0, acc[i][ni], 0, 0, 0);
            acc[i][ni] = __builtin_amdgcn_mfma_f32_16x16x32_bf16(vf.v1[ni], pa1, acc[i][ni], 0, 0, 0);
        }
    }
    __builtin_amdgcn_s_setprio(0);

    // ---- deferred psum cross-lane reduce (hides under PV issue) ----
    #pragma unroll
    for (int i = 0; i < 4; ++i) {
        float ps = psum_t[i];
        ps += __shfl_xor(ps, 16);
        ps += __shfl_xor(ps, 32);
        l_acc[i] = l_acc[i] * sc_t[i] + ps;
    }
}

// ---------------------------------------------------------------------------
// Causal flash attention: QUAD of 16-row q-tiles (64 rows) per 1-wave block.
// K register-double-buffered across iterations (named sets, uniform parity
// branch); V early-issued per iteration; pair-wise stage-major softmax;
// deferred l-reduction. Grid 2048 waves, longest-first, heads pinned to XCD.
// ---------------------------------------------------------------------------
__global__ __launch_bounds__(64, 2) void attn_kernel(
    const __bf16* __restrict__ q, const __bf16* __restrict__ k,
    const __bf16* __restrict__ vt, float* __restrict__ out)
{
    __shared__ __bf16 plds[4][16][64];

    const int l  = threadIdx.x;
    const int lr = l & 15;
    const int lg = l >> 4;
    const int lk = lg * 8;
    const int swz = (lr & 7) << 3;

    const int n   = blockIdx.x;
    const int xcd = n & 7;
    const int m   = n >> 3;              // 0..255
    const int qq  = 31 - (m >> 3);       // quad index, longest first
    const int bh  = xcd * 8 + (m & 7);

    const __bf16* __restrict__ kp = k  + (size_t)bh * S_LEN * HDIM;
    const __bf16* __restrict__ vp = vt + (size_t)bh * HDIM * S_LEN;
    const int bq = bh >> 4;
    const int hq = bh & 15;

    const int qbase = qq * 64;
    const int iters = qq + 1;

    const __bf16* __restrict__ qp = q + ((size_t)bh * S_LEN + qbase) * HDIM;
    bf16x8 bq0[4], bq1[4];
    #pragma unroll
    for (int i = 0; i < 4; ++i) {
        bq0[i] = *reinterpret_cast<const bf16x8*>(qp + (size_t)(i * 16 + lr) * HDIM + lk);
        bq1[i] = *reinterpret_cast<const bf16x8*>(qp + (size_t)(i * 16 + lr) * HDIM + 32 + lk);
    }

    float m_acc[4], l_acc[4];
    f32x4 acc[4][4] = {};
    #pragma unroll
    for (int i = 0; i < 4; ++i) { m_acc[i] = -1e30f; l_acc[i] = 0.0f; }

    __bf16* pl_base = &plds[0][0][0];

    KFrag kA, kB;
    load_k(kA, kp, 0, lr, lk);
    bool useA = true;

    #pragma unroll 1
    for (int j = 0; j < iters - 1; ++j) {
        if (useA) {
            load_k(kB, kp, (j + 1) * 64, lr, lk);       // prefetch next
            quad_compute<false>(j * 64, qbase, lr, lg, lk, swz, vp, kA,
                                bq0, bq1, m_acc, l_acc, acc, pl_base);
        } else {
            load_k(kA, kp, (j + 1) * 64, lr, lk);
            quad_compute<false>(j * 64, qbase, lr, lg, lk, swz, vp, kB,
                                bq0, bq1, m_acc, l_acc, acc, pl_base);
        }
        useA = !useA;
    }
    if (useA)
        quad_compute<true>((iters - 1) * 64, qbase, lr, lg, lk, swz, vp, kA,
                           bq0, bq1, m_acc, l_acc, acc, pl_base);
    else
        quad_compute<true>((iters - 1) * 64, qbase, lr, lg, lk, swz, vp, kB,
                           bq0, bq1, m_acc, l_acc, acc, pl_base);

    // ---- epilogue: tile i, lane's q-row = qbase + 16i + lr ----
    #pragma unroll
    for (int i = 0; i < 4; ++i) {
        const float liv = 1.0f / l_acc[i];
        float* orow = out + (size_t)(bq * S_LEN + qbase + i * 16 + lr) * D_DIM + hq * HDIM;
        #pragma unroll
        for (int ni = 0; ni < 4; ++ni) {
            f32x4 ox;
            #pragma unroll
            for (int r = 0; r < 4; ++r) ox[r] = acc[i][ni][r] * liv;
            *reinterpret_cast<f32x4*>(orow + ni * 16 + lg * 4) = ox;
        }
    }
}

extern "C" void kernel_launch(void* const* d_in, const int* in_sizes, int n_in,
                              void* d_out, int out_size, void* d_ws, size_t ws_size,
                              hipStream_t stream)
{
    const float* x  = (const float*)d_in[0];
    const float* Wq = (const float*)d_in[1];
    const float* Wk = (const float*)d_in[2];
    const float* Wv = (const float*)d_in[3];
    float* out = (float*)d_out;

    const size_t x_elems = (size_t)BATCH * S_LEN * D_DIM;
    const size_t w_elems = (size_t)D_DIM * D_DIM;
    __bf16* xb   = (__bf16*)d_out;          // scratch in d_out (overwritten)
    __bf16* wcat = xb + x_elems;

    const size_t per_buf = (size_t)BATCH * NHEAD * S_LEN * HDIM;
    __bf16* qb = (__bf16*)d_ws;
    __bf16* kb = qb + per_buf;
    __bf16* vb = kb + per_buf;

    cvt_kernel<<<(int)(x_elems / 8 / 256), 256, 0, stream>>>(x, xb, (int)(x_elems / 8));
    cvt_kernel<<<(int)(w_elems / 8 / 256), 256, 0, stream>>>(Wq, wcat, (int)(w_elems / 8));
    cvt_kernel<<<(int)(w_elems / 8 / 256), 256, 0, stream>>>(Wk, wcat + w_elems, (int)(w_elems / 8));
    cvt_kernel<<<(int)(w_elems / 8 / 256), 256, 0, stream>>>(Wv, wcat + 2 * w_elems, (int)(w_elems / 8));

    dim3 grid1(3 * D_DIM / 128, (BATCH * S_LEN) / 128);   // (24, 64)
    proj_gemm_kernel<<<grid1, dim3(256), 0, stream>>>(xb, wcat, qb, kb, vb);

    attn_kernel<<<dim3(2048), dim3(64), 0, stream>>>(qb, kb, vb, out);
}

// Round 9
// 197.458 us; speedup vs baseline: 1.8019x; 1.8019x over previous
//
#include <hip/hip_runtime.h>
#include <hip/hip_bf16.h>

#define BATCH 4
#define S_LEN 2048
#define D_DIM 1024
#define NHEAD 16
#define HDIM 64

// Q pre-scale: 1/sqrt(HDIM) * log2(e), so softmax works in exp2 domain.
#define QSCALE 0.18033688011112042f

typedef __attribute__((ext_vector_type(8))) __bf16 bf16x8;
typedef __attribute__((ext_vector_type(4))) __bf16 bf16x4;
typedef __attribute__((ext_vector_type(4))) float f32x4;

static __device__ inline unsigned int bf16_bits(float f) {
    __bf16 h = (__bf16)f;
    return (unsigned int)__builtin_bit_cast(unsigned short, h);
}

// ---------------------------------------------------------------------------
// fp32 -> bf16 bulk convert, 8 elems/thread, 16B stores.
// ---------------------------------------------------------------------------
__global__ __launch_bounds__(256) void cvt_kernel(
    const float* __restrict__ src, __bf16* __restrict__ dst, int n8)
{
    int i = blockIdx.x * 256 + threadIdx.x;
    if (i >= n8) return;
    const f32x4* p = reinterpret_cast<const f32x4*>(src + (size_t)i * 8);
    f32x4 a = p[0], b = p[1];
    bf16x8 r;
    r[0] = (__bf16)a[0]; r[1] = (__bf16)a[1]; r[2] = (__bf16)a[2]; r[3] = (__bf16)a[3];
    r[4] = (__bf16)b[0]; r[5] = (__bf16)b[1]; r[6] = (__bf16)b[2]; r[7] = (__bf16)b[3];
    *reinterpret_cast<bf16x8*>(dst + (size_t)i * 8) = r;
}

// ---------------------------------------------------------------------------
// Projection GEMM (m97-style): C[m][n] = sum_d xb[m][d] * wb[n][d]
// q output is pre-scaled by QSCALE. q,k -> [bh][s][e]; v -> [bh][e][s].
// ---------------------------------------------------------------------------
__global__ __launch_bounds__(256) void proj_gemm_kernel(
    const __bf16* __restrict__ xb, const __bf16* __restrict__ wb,
    __bf16* __restrict__ qo, __bf16* __restrict__ ko, __bf16* __restrict__ vto)
{
    __shared__ __bf16 As[128][32];
    __shared__ __bf16 Bs[128][32];

    const int tid = threadIdx.x;
    const int l  = tid & 63;
    const int w  = tid >> 6;
    const int wm = w >> 1, wn = w & 1;
    const int lr = l & 15, lg = l >> 4, lk = lg * 8;
    const int m0 = blockIdx.y * 128;
    const int n0 = blockIdx.x * 128;
    const int mat = n0 >> 10;           // 0=q,1=k,2=v
    const int nb  = n0 & 1023;

    const int sr = l >> 2;
    const int sc = (l & 3) * 8;
    const int g0 = w * 2;

    f32x4 acc[4][4] = {};

    for (int d = 0; d < D_DIM; d += 32) {
        __builtin_amdgcn_global_load_lds(
            (const __attribute__((address_space(1))) void*)(xb + (size_t)(m0 + g0 * 16 + sr) * D_DIM + d + sc),
            (__attribute__((address_space(3))) void*)(&As[g0 * 16][0]), 16, 0, 0);
        __builtin_amdgcn_global_load_lds(
            (const __attribute__((address_space(1))) void*)(xb + (size_t)(m0 + (g0 + 1) * 16 + sr) * D_DIM + d + sc),
            (__attribute__((address_space(3))) void*)(&As[(g0 + 1) * 16][0]), 16, 0, 0);
        __builtin_amdgcn_global_load_lds(
            (const __attribute__((address_space(1))) void*)(wb + (size_t)(n0 + g0 * 16 + sr) * D_DIM + d + sc),
            (__attribute__((address_space(3))) void*)(&Bs[g0 * 16][0]), 16, 0, 0);
        __builtin_amdgcn_global_load_lds(
            (const __attribute__((address_space(1))) void*)(wb + (size_t)(n0 + (g0 + 1) * 16 + sr) * D_DIM + d + sc),
            (__attribute__((address_space(3))) void*)(&Bs[(g0 + 1) * 16][0]), 16, 0, 0);
        __syncthreads();

        bf16x8 af[4], bfr[4];
        #pragma unroll
        for (int mi = 0; mi < 4; ++mi)
            af[mi] = *reinterpret_cast<const bf16x8*>(&As[wm * 64 + mi * 16 + lr][lk]);
        #pragma unroll
        for (int ni = 0; ni < 4; ++ni)
            bfr[ni] = *reinterpret_cast<const bf16x8*>(&Bs[wn * 64 + ni * 16 + lr][lk]);
        #pragma unroll
        for (int mi = 0; mi < 4; ++mi) {
            #pragma unroll
            for (int ni = 0; ni < 4; ++ni)
                acc[mi][ni] = __builtin_amdgcn_mfma_f32_16x16x32_bf16(
                    af[mi], bfr[ni], acc[mi][ni], 0, 0, 0);
        }
        __syncthreads();
    }

    const float oscale = (mat == 0) ? QSCALE : 1.0f;
    #pragma unroll
    for (int mi = 0; mi < 4; ++mi) {
        const int mrow = m0 + wm * 64 + mi * 16 + lg * 4;
        const int b = mrow >> 11;
        const int s = mrow & (S_LEN - 1);
        #pragma unroll
        for (int ni = 0; ni < 4; ++ni) {
            const int n = nb + wn * 64 + ni * 16 + lr;
            const int h = n >> 6;
            const int e = n & 63;
            if (mat == 2) {
                bf16x4 pk;
                #pragma unroll
                for (int r = 0; r < 4; ++r) pk[r] = (__bf16)acc[mi][ni][r];
                *reinterpret_cast<bf16x4*>(
                    vto + ((size_t)(b * NHEAD + h) * HDIM + e) * S_LEN + s) = pk;
            } else {
                __bf16* __restrict__ dst = (mat == 0) ? qo : ko;
                #pragma unroll
                for (int r = 0; r < 4; ++r)
                    dst[((size_t)(b * NHEAD + h) * S_LEN + (s + r)) * HDIM + e] =
                        (__bf16)(acc[mi][ni][r] * oscale);
            }
        }
    }
}

// ---------------------------------------------------------------------------
// Async K-tile staging: 64 rows x 64 elems bf16 -> linear LDS [64][64],
// bank-swizzled via PRE-SWIZZLED GLOBAL SOURCE (global_load_lds writes
// linearly: base + lane*16B). LDS[row][cb] = K[row][cb ^ ((row&7)<<4)]
// (byte units). 8 chunks of 1KB; zero VGPR cost; vmcnt-counted.
// ---------------------------------------------------------------------------
__device__ __attribute__((always_inline)) inline void stage_k(
    __bf16* kbuf, const __bf16* __restrict__ kp, int kv0, int l)
{
    const int rsub = l >> 3;                       // 0..7
    const int csw  = ((l & 7) ^ rsub) << 3;        // swizzled col (elems)
    #pragma unroll
    for (int ch = 0; ch < 8; ++ch) {
        __builtin_amdgcn_global_load_lds(
            (const __attribute__((address_space(1))) void*)(
                kp + (size_t)(kv0 + ch * 8 + rsub) * HDIM + csw),
            (__attribute__((address_space(3))) void*)(kbuf + ch * 512),
            16, 0, 0);
    }
}

// ---------------------------------------------------------------------------
// One KV iteration (64 kv) for a QUAD of 16-row q-tiles. K comes from the
// prefetched LDS buffer (swizzled reads); V loaded global->reg at top
// (covered by QK+softmax). Swapped QK^T and swapped PV as before.
// ---------------------------------------------------------------------------
template<bool MASK>
__device__ __attribute__((always_inline)) inline void quad_compute(
    int kv0, int qbase, int lr, int lg, int lk, int swz,
    const __bf16* __restrict__ vp, const __bf16* __restrict__ kb,
    const bf16x8 (&bq0)[4], const bf16x8 (&bq1)[4],
    float (&m_acc)[4], float (&l_acc)[4], f32x4 (&acc)[4][4],
    __bf16* pl_base)
{
    // K-LDS fragment columns (swizzle-inverted)
    const int kcol0 = (lg * 8) ^ ((lr & 7) << 3);
    const int kcol1 = (32 + lg * 8) ^ ((lr & 7) << 3);

    // ---- V early issue (consumed only at PV) ----
    bf16x8 av[2][4];
    #pragma unroll
    for (int ni = 0; ni < 4; ++ni) {
        const __bf16* vrow = vp + (size_t)(ni * 16 + lr) * S_LEN + kv0;
        av[0][ni] = *reinterpret_cast<const bf16x8*>(vrow + lk);
        av[1][ni] = *reinterpret_cast<const bf16x8*>(vrow + 32 + lk);
    }

    // ---- per-tile QK^T + branch-free online softmax ----
    #pragma unroll
    for (int i = 0; i < 4; ++i) {
        __bf16* pl = pl_base + i * (16 * 64);
        f32x4 s[4];
        __builtin_amdgcn_s_setprio(1);
        #pragma unroll
        for (int c = 0; c < 4; ++c) {
            const int row = c * 16 + lr;
            const bf16x8 ka0 = *reinterpret_cast<const bf16x8*>(kb + row * 64 + kcol0);
            const bf16x8 ka1 = *reinterpret_cast<const bf16x8*>(kb + row * 64 + kcol1);
            f32x4 tt = {};
            tt = __builtin_amdgcn_mfma_f32_16x16x32_bf16(ka0, bq0[i], tt, 0, 0, 0);
            tt = __builtin_amdgcn_mfma_f32_16x16x32_bf16(ka1, bq1[i], tt, 0, 0, 0);
            s[c] = tt;
        }
        __builtin_amdgcn_s_setprio(0);

        if (MASK) {
            const int qrow = qbase + i * 16 + lr;
            #pragma unroll
            for (int c = 0; c < 4; ++c)
                #pragma unroll
                for (int r = 0; r < 4; ++r)
                    if (kv0 + c * 16 + lg * 4 + r > qrow) s[c][r] = -1e30f;
        }

        float a0 = fmaxf(fmaxf(s[0][0], s[0][1]), fmaxf(s[0][2], s[0][3]));
        float a1 = fmaxf(fmaxf(s[1][0], s[1][1]), fmaxf(s[1][2], s[1][3]));
        float a2 = fmaxf(fmaxf(s[2][0], s[2][1]), fmaxf(s[2][2], s[2][3]));
        float a3 = fmaxf(fmaxf(s[3][0], s[3][1]), fmaxf(s[3][2], s[3][3]));
        float mx = fmaxf(fmaxf(a0, a1), fmaxf(a2, a3));
        mx = fmaxf(mx, __shfl_xor(mx, 16));
        mx = fmaxf(mx, __shfl_xor(mx, 32));

        const float mnew = fmaxf(m_acc[i], mx);
        const float sc = exp2f(m_acc[i] - mnew);
        m_acc[i] = mnew;

        float psum = 0.0f;
        #pragma unroll
        for (int c = 0; c < 4; ++c) {
            const float p0 = exp2f(s[c][0] - mnew);
            const float p1 = exp2f(s[c][1] - mnew);
            const float p2 = exp2f(s[c][2] - mnew);
            const float p3 = exp2f(s[c][3] - mnew);
            psum += (p0 + p1) + (p2 + p3);
            uint2 pk;
            pk.x = bf16_bits(p0) | (bf16_bits(p1) << 16);
            pk.y = bf16_bits(p2) | (bf16_bits(p3) << 16);
            *reinterpret_cast<uint2*>(pl + lr * 64 + ((c * 16 + lg * 4) ^ swz)) = pk;
        }
        psum += __shfl_xor(psum, 16);
        psum += __shfl_xor(psum, 32);
        l_acc[i] = l_acc[i] * sc + psum;

        #pragma unroll
        for (int ni = 0; ni < 4; ++ni) acc[i][ni] *= sc;   // per-lane q-row
    }

    // ---- PV (swapped): shared V fragments, acc cols = own q-row ----
    __builtin_amdgcn_s_setprio(1);
    #pragma unroll
    for (int c2 = 0; c2 < 2; ++c2) {
        #pragma unroll
        for (int i = 0; i < 4; ++i) {
            __bf16* pl = pl_base + i * (16 * 64);
            const bf16x8 pa = *reinterpret_cast<const bf16x8*>(
                pl + lr * 64 + ((c2 * 32 + lk) ^ swz));
            #pragma unroll
            for (int ni = 0; ni < 4; ++ni)
                acc[i][ni] = __builtin_amdgcn_mfma_f32_16x16x32_bf16(
                    av[c2][ni], pa, acc[i][ni], 0, 0, 0);
        }
    }
    __builtin_amdgcn_s_setprio(0);
}

// ---------------------------------------------------------------------------
// Causal flash attention: QUAD of 16-row q-tiles (64 rows) per 1-wave block
// (R7 structure, 124us) + LDS double-buffered async K prefetch (zero VGPR,
// counted vmcnt: 8 loads stay in flight across the iteration; drained to 0
// only at prologue and last iteration). sched_barrier(0) fences per rule #18.
// ---------------------------------------------------------------------------
__global__ __launch_bounds__(64, 2) void attn_kernel(
    const __bf16* __restrict__ q, const __bf16* __restrict__ k,
    const __bf16* __restrict__ vt, float* __restrict__ out)
{
    __shared__ __bf16 plds[4][16][64];     // 8 KB P buffer
    __shared__ __bf16 klds[2][64 * 64];    // 16 KB K double buffer

    const int l  = threadIdx.x;
    const int lr = l & 15;
    const int lg = l >> 4;
    const int lk = lg * 8;
    const int swz = (lr & 7) << 3;

    const int n   = blockIdx.x;
    const int xcd = n & 7;
    const int m   = n >> 3;              // 0..255
    const int qq  = 31 - (m >> 3);       // quad index, longest first
    const int bh  = xcd * 8 + (m & 7);

    const __bf16* __restrict__ kp = k  + (size_t)bh * S_LEN * HDIM;
    const __bf16* __restrict__ vp = vt + (size_t)bh * HDIM * S_LEN;
    const int bq = bh >> 4;
    const int hq = bh & 15;

    const int qbase = qq * 64;
    const int iters = qq + 1;

    const __bf16* __restrict__ qp = q + ((size_t)bh * S_LEN + qbase) * HDIM;
    bf16x8 bq0[4], bq1[4];
    #pragma unroll
    for (int i = 0; i < 4; ++i) {
        bq0[i] = *reinterpret_cast<const bf16x8*>(qp + (size_t)(i * 16 + lr) * HDIM + lk);
        bq1[i] = *reinterpret_cast<const bf16x8*>(qp + (size_t)(i * 16 + lr) * HDIM + 32 + lk);
    }

    float m_acc[4], l_acc[4];
    f32x4 acc[4][4] = {};
    #pragma unroll
    for (int i = 0; i < 4; ++i) { m_acc[i] = -1e30f; l_acc[i] = 0.0f; }

    __bf16* pl_base = &plds[0][0][0];

    // ---- prologue: stage K(0), drain ----
    stage_k(&klds[0][0], kp, 0, l);
    asm volatile("s_waitcnt vmcnt(0)" ::: "memory");
    __builtin_amdgcn_sched_barrier(0);

    #pragma unroll 1
    for (int j = 0; j < iters - 1; ++j) {
        // prefetch next K tile into the other buffer (async, stays in flight)
        stage_k(&klds[(j & 1) ^ 1][0], kp, (j + 1) * 64, l);
        __builtin_amdgcn_sched_barrier(0);
        asm volatile("s_waitcnt vmcnt(8)" ::: "memory");  // K(j) resident
        __builtin_amdgcn_sched_barrier(0);
        quad_compute<false>(j * 64, qbase, lr, lg, lk, swz, vp, &klds[j & 1][0],
                            bq0, bq1, m_acc, l_acc, acc, pl_base);
    }
    // ---- peeled masked last iteration (no further prefetch) ----
    __builtin_amdgcn_sched_barrier(0);
    asm volatile("s_waitcnt vmcnt(0)" ::: "memory");
    __builtin_amdgcn_sched_barrier(0);
    quad_compute<true>((iters - 1) * 64, qbase, lr, lg, lk, swz, vp,
                       &klds[(iters - 1) & 1][0],
                       bq0, bq1, m_acc, l_acc, acc, pl_base);

    // ---- epilogue: tile i, lane's q-row = qbase + 16i + lr ----
    #pragma unroll
    for (int i = 0; i < 4; ++i) {
        const float liv = 1.0f / l_acc[i];
        float* orow = out + (size_t)(bq * S_LEN + qbase + i * 16 + lr) * D_DIM + hq * HDIM;
        #pragma unroll
        for (int ni = 0; ni < 4; ++ni) {
            f32x4 ox;
            #pragma unroll
            for (int r = 0; r < 4; ++r) ox[r] = acc[i][ni][r] * liv;
            *reinterpret_cast<f32x4*>(orow + ni * 16 + lg * 4) = ox;
        }
    }
}

extern "C" void kernel_launch(void* const* d_in, const int* in_sizes, int n_in,
                              void* d_out, int out_size, void* d_ws, size_t ws_size,
                              hipStream_t stream)
{
    const float* x  = (const float*)d_in[0];
    const float* Wq = (const float*)d_in[1];
    const float* Wk = (const float*)d_in[2];
    const float* Wv = (const float*)d_in[3];
    float* out = (float*)d_out;

    const size_t x_elems = (size_t)BATCH * S_LEN * D_DIM;
    const size_t w_elems = (size_t)D_DIM * D_DIM;
    __bf16* xb   = (__bf16*)d_out;          // scratch in d_out (overwritten)
    __bf16* wcat = xb + x_elems;

    const size_t per_buf = (size_t)BATCH * NHEAD * S_LEN * HDIM;
    __bf16* qb = (__bf16*)d_ws;
    __bf16* kb = qb + per_buf;
    __bf16* vb = kb + per_buf;

    cvt_kernel<<<(int)(x_elems / 8 / 256), 256, 0, stream>>>(x, xb, (int)(x_elems / 8));
    cvt_kernel<<<(int)(w_elems / 8 / 256), 256, 0, stream>>>(Wq, wcat, (int)(w_elems / 8));
    cvt_kernel<<<(int)(w_elems / 8 / 256), 256, 0, stream>>>(Wk, wcat + w_elems, (int)(w_elems / 8));
    cvt_kernel<<<(int)(w_elems / 8 / 256), 256, 0, stream>>>(Wv, wcat + 2 * w_elems, (int)(w_elems / 8));

    dim3 grid1(3 * D_DIM / 128, (BATCH * S_LEN) / 128);   // (24, 64)
    proj_gemm_kernel<<<grid1, dim3(256), 0, stream>>>(xb, wcat, qb, kb, vb);

    attn_kernel<<<dim3(2048), dim3(64), 0, stream>>>(qb, kb, vb, out);
}